// Round 1
// baseline (115.010 us; speedup 1.0000x reference)
//
#include <hip/hip_runtime.h>
#include <hip/hip_bf16.h>

typedef __bf16 bf16x8 __attribute__((ext_vector_type(8)));
typedef float  f32x4  __attribute__((ext_vector_type(4)));

#define B_SZ 1024
#define D_SZ 128
#define C_SZ 100000
#define BM 128
#define BN 128
#define NCT 782   // ceil(100000/128)

#define SCALE_F   64.0f
#define MARGIN_F  0.35f
#define CLIP_F    (1.0f - 1e-7f)
#define LOG2E_F   1.4426950408889634f
#define S_LOG2E_F (64.0f * 1.4426950408889634f)

struct bf2 { __bf16 x, y; };

__device__ __forceinline__ void gload_lds16(const void* g, void* l) {
    __builtin_amdgcn_global_load_lds(
        (const __attribute__((address_space(1))) void*)g,
        (__attribute__((address_space(3))) void*)l, 16, 0, 0);
}

// ---------------- Kernel A: L2-normalize W rows, emit bf16 ----------------
__global__ void norm_w(const float* __restrict__ W, __bf16* __restrict__ Wb) {
    const int row  = blockIdx.x * 4 + (threadIdx.x >> 6);
    const int lane = threadIdx.x & 63;
    if (row >= C_SZ) return;
    float2 v = reinterpret_cast<const float2*>(W + (size_t)row * D_SZ)[lane];
    float ss = v.x * v.x + v.y * v.y;
    #pragma unroll
    for (int m = 1; m < 64; m <<= 1) ss += __shfl_xor(ss, m);
    float sc = 1.0f / fmaxf(sqrtf(ss), 1e-12f);
    bf2 o; o.x = (__bf16)(v.x * sc); o.y = (__bf16)(v.y * sc);
    reinterpret_cast<bf2*>(Wb + (size_t)row * D_SZ)[lane] = o;
}

// ---------------- Kernel B: convert embeddings to bf16 ----------------
__global__ void conv_e(const float* __restrict__ E, __bf16* __restrict__ Eb) {
    const int i = blockIdx.x * 256 + threadIdx.x;   // 65536 threads x float2
    float2 v = reinterpret_cast<const float2*>(E)[i];
    bf2 o; o.x = (__bf16)v.x; o.y = (__bf16)v.y;
    reinterpret_cast<bf2*>(Eb)[i] = o;
}

// ------- Kernel C: fused bf16 MFMA GEMM + clip/scale/exp + row partials -------
// grid = (8 B-tiles [fast], 782 C-tiles), 256 threads (4 waves, 2x2)
__launch_bounds__(256, 2)
__global__ void gemm_lse(const __bf16* __restrict__ Eb, const __bf16* __restrict__ Wb,
                         float* __restrict__ P) {
    __shared__ __bf16 sA[BM * D_SZ];   // 32 KB, XOR-swizzled: byte ^= (row&7)<<4
    __shared__ __bf16 sB[BN * D_SZ];   // 32 KB
    __shared__ float  rs[2][BM];

    const int tid  = threadIdx.x;
    const int wave = tid >> 6;
    const int lane = tid & 63;
    const int bi   = blockIdx.x;       // B tile 0..7
    const int ci   = blockIdx.y;       // C tile 0..781

    // ---- stage A and B tiles via global_load_lds (16B/lane), source pre-swizzled
    {
        const char* ebase = reinterpret_cast<const char*>(Eb) + (size_t)bi * BM * D_SZ * 2;
        const char* wbase = reinterpret_cast<const char*>(Wb);
        char* sa = reinterpret_cast<char*>(sA);
        char* sb = reinterpret_cast<char*>(sB);
        #pragma unroll
        for (int j = 0; j < 8; ++j) {
            const int p    = j * 4096 + tid * 16;         // physical LDS byte
            const int row  = p >> 8;                      // tile row (256B rows)
            const int swin = (p & 255) ^ ((row & 7) << 4);// logical in-row byte
            // A: rows always valid (B=1024 divisible by 128)
            gload_lds16(ebase + (row << 8) + swin, sa + (j * 4096 + wave * 1024));
            // B: clamp class row on the tail tile
            int grow = ci * BN + row;
            if (grow >= C_SZ) grow = C_SZ - 1;
            gload_lds16(wbase + ((size_t)grow << 8) + swin, sb + (j * 4096 + wave * 1024));
        }
    }
    __syncthreads();   // drains vmcnt before any ds_read

    const int g4  = lane >> 4;   // 0..3
    const int l15 = lane & 15;
    const int wm  = wave >> 1, wn = wave & 1;

    f32x4 acc[4][4] = {};
    const char* sAb = reinterpret_cast<const char*>(sA);
    const char* sBb = reinterpret_cast<const char*>(sB);

    #pragma unroll
    for (int kk = 0; kk < 4; ++kk) {
        const int kbyte = kk * 64 + g4 * 16;   // (kk*32 + g4*8) bf16 elems
        bf16x8 a[4], b[4];
        #pragma unroll
        for (int mi = 0; mi < 4; ++mi) {
            const int row = wm * 64 + mi * 16 + l15;
            a[mi] = *reinterpret_cast<const bf16x8*>(sAb + row * 256 + (kbyte ^ ((row & 7) << 4)));
        }
        #pragma unroll
        for (int ni = 0; ni < 4; ++ni) {
            const int row = wn * 64 + ni * 16 + l15;
            b[ni] = *reinterpret_cast<const bf16x8*>(sBb + row * 256 + (kbyte ^ ((row & 7) << 4)));
        }
        #pragma unroll
        for (int mi = 0; mi < 4; ++mi)
            #pragma unroll
            for (int ni = 0; ni < 4; ++ni)
                acc[mi][ni] = __builtin_amdgcn_mfma_f32_16x16x32_bf16(a[mi], b[ni], acc[mi][ni], 0, 0, 0);
    }

    // ---- epilogue: t = exp(64*clip(cos) - 64), per-row sums over this tile's cols
    #pragma unroll
    for (int mi = 0; mi < 4; ++mi) {
        #pragma unroll
        for (int r = 0; r < 4; ++r) {
            float s = 0.0f;
            #pragma unroll
            for (int ni = 0; ni < 4; ++ni) {
                const int col = ci * BN + wn * 64 + ni * 16 + l15;
                float x = acc[mi][ni][r];
                x = fminf(fmaxf(x, -CLIP_F), CLIP_F);
                float t = exp2f(fmaf(x, S_LOG2E_F, -S_LOG2E_F));
                s += (col < C_SZ) ? t : 0.0f;
            }
            // reduce across the 16 lanes sharing this output row
            s += __shfl_xor(s, 1);
            s += __shfl_xor(s, 2);
            s += __shfl_xor(s, 4);
            s += __shfl_xor(s, 8);
            if (l15 == 0) rs[wn][wm * 64 + mi * 16 + g4 * 4 + r] = s;
        }
    }
    __syncthreads();
    if (tid < BM) {
        const float s = rs[0][tid] + rs[1][tid];
        P[(size_t)ci * B_SZ + bi * BM + tid] = s;
    }
}

// ------- Kernel D1: per-row S reduce + target dot + nll -------
__global__ void row_fin(const float* __restrict__ P, const __bf16* __restrict__ Eb,
                        const __bf16* __restrict__ Wb, const int* __restrict__ lab,
                        float* __restrict__ nll) {
    __shared__ float red[256];
    const int row = blockIdx.x;
    const int t   = threadIdx.x;

    float s = 0.0f;
    for (int ci = t; ci < NCT; ci += 256) s += P[(size_t)ci * B_SZ + row];
    red[t] = s;
    __syncthreads();
    #pragma unroll
    for (int off = 128; off > 0; off >>= 1) {
        if (t < off) red[t] += red[t + off];
        __syncthreads();
    }
    const float S = red[0];
    __syncthreads();

    const int lb = lab[row];
    float d = 0.0f;
    if (t < 128) d = (float)Eb[row * D_SZ + t] * (float)Wb[(size_t)lb * D_SZ + t];
    red[t] = d;
    __syncthreads();
    #pragma unroll
    for (int off = 128; off > 0; off >>= 1) {
        if (t < off) red[t] += red[t + off];
        __syncthreads();
    }

    if (t == 0) {
        const float ct = red[0];
        const float cc = fminf(fmaxf(ct, -CLIP_F), CLIP_F);
        const float lt = SCALE_F * (cc - MARGIN_F);
        float Sadj = S - exp2f((SCALE_F * cc - SCALE_F) * LOG2E_F)
                       + exp2f((lt - SCALE_F) * LOG2E_F);
        nll[row] = SCALE_F + logf(Sadj) - lt;
    }
}

// ------- Kernel D2: mean over 1024 rows -------
__global__ void mean_k(const float* __restrict__ nll, float* __restrict__ out) {
    __shared__ float red[1024];
    const int t = threadIdx.x;
    red[t] = nll[t];
    __syncthreads();
    #pragma unroll
    for (int off = 512; off > 0; off >>= 1) {
        if (t < off) red[t] += red[t + off];
        __syncthreads();
    }
    if (t == 0) out[0] = red[0] * (1.0f / 1024.0f);
}

extern "C" void kernel_launch(void* const* d_in, const int* in_sizes, int n_in,
                              void* d_out, int out_size, void* d_ws, size_t ws_size,
                              hipStream_t stream) {
    const float* E   = (const float*)d_in[0];
    const int*   lab = (const int*)d_in[1];
    const float* W   = (const float*)d_in[2];
    float*       out = (float*)d_out;

    char* ws = (char*)d_ws;
    __bf16* Eb  = (__bf16*)ws;                                   // 262144 B
    __bf16* Wb  = (__bf16*)(ws + 262144);                        // 25,600,000 B
    float*  P   = (float*)(ws + 262144 + 25600000);              // 3,203,072 B
    float*  nll = (float*)(ws + 262144 + 25600000 + 3203072);    // 4096 B

    norm_w  <<<dim3(25000),    256,  0, stream>>>(W, Wb);
    conv_e  <<<dim3(256),      256,  0, stream>>>(E, Eb);
    gemm_lse<<<dim3(8, NCT),   256,  0, stream>>>(Eb, Wb, P);
    row_fin <<<dim3(B_SZ),     256,  0, stream>>>(P, Eb, Wb, lab, nll);
    mean_k  <<<dim3(1),        1024, 0, stream>>>(nll, out);
}

// Round 2
// 71.320 us; speedup vs baseline: 1.6126x; 1.6126x over previous
//
#include <hip/hip_runtime.h>
#include <hip/hip_bf16.h>

typedef __bf16 bf16x8 __attribute__((ext_vector_type(8)));
typedef float  f32x4  __attribute__((ext_vector_type(4)));

#define B_SZ 1024
#define D_SZ 128
#define C_SZ 100000
#define CPAD 100096          // padded class rows (zero tail), 782*128 = 100096
#define BM 256
#define BN 128
#define NG 64                // C-tile groups (grid.x)
#define NCT 782              // ceil(100000/128)

#define SCALE_F   64.0f
#define MARGIN_F  0.35f
#define CLIP_F    (1.0f - 1e-7f)
#define LOG2E_F   1.4426950408889634f
#define S_LOG2E_F (64.0f * 1.4426950408889634f)

struct bf2 { __bf16 x, y; };

__device__ __forceinline__ void gload_lds16(const void* g, void* l) {
    __builtin_amdgcn_global_load_lds(
        (const __attribute__((address_space(1))) void*)g,
        (__attribute__((address_space(3))) void*)l, 16, 0, 0);
}

// ---- Kernel A: L2-normalize W rows -> bf16 (+zero pad rows) + convert E -> bf16
__global__ void norm_conv(const float* __restrict__ W, __bf16* __restrict__ Wb,
                          const float* __restrict__ E, __bf16* __restrict__ Eb) {
    const int b = blockIdx.x;
    if (b < 25024) {
        const int row  = b * 4 + (threadIdx.x >> 6);
        const int lane = threadIdx.x & 63;
        if (row < C_SZ) {
            float2 v = reinterpret_cast<const float2*>(W + (size_t)row * D_SZ)[lane];
            float ss = v.x * v.x + v.y * v.y;
            #pragma unroll
            for (int m = 1; m < 64; m <<= 1) ss += __shfl_xor(ss, m);
            float sc = 1.0f / fmaxf(sqrtf(ss), 1e-12f);
            bf2 o; o.x = (__bf16)(v.x * sc); o.y = (__bf16)(v.y * sc);
            reinterpret_cast<bf2*>(Wb + (size_t)row * D_SZ)[lane] = o;
        } else if (row < CPAD) {
            bf2 z; z.x = (__bf16)0.0f; z.y = (__bf16)0.0f;
            reinterpret_cast<bf2*>(Wb + (size_t)row * D_SZ)[lane] = z;
        }
    } else {
        const int i = (b - 25024) * 256 + threadIdx.x;   // 65536 float2
        float2 v = reinterpret_cast<const float2*>(E)[i];
        bf2 o; o.x = (__bf16)v.x; o.y = (__bf16)v.y;
        reinterpret_cast<bf2*>(Eb)[i] = o;
    }
}

// ---- Kernel C: persistent-ish fused GEMM + exp-sum.
// grid = (NG=64 groups, 4 B-tiles), 512 threads (8 waves, 4x2).
// Each block: stage A(256x128) once, hold A-frags in regs, loop C-tiles
// (ci = g + t*64) with double-buffered B staging. Per-thread exp-sums
// accumulate in registers; one reduce + write at the end.
__launch_bounds__(512, 2)
__global__ void gemm_lse(const __bf16* __restrict__ Eb, const __bf16* __restrict__ Wb,
                         float* __restrict__ P) {
    __shared__ __bf16 sA[BM * D_SZ];      // 64 KB, XOR-swizzled: byte ^= (row&7)<<4
    __shared__ __bf16 sB[2][BN * D_SZ];   // 2 x 32 KB, same swizzle

    const int tid  = threadIdx.x;
    const int wave = tid >> 6;
    const int lane = tid & 63;
    const int g4   = lane >> 4;
    const int l15  = lane & 15;
    const int wm   = wave >> 1;           // 0..3 : 64-row slice
    const int wn   = wave & 1;            // 0..1 : 64-col slice
    const int g    = blockIdx.x;          // 0..63
    const int bi   = blockIdx.y;          // 0..3

    const int T = (NCT - g + NG - 1) / NG;   // 13 for g<=13, else 12

    const char* ebase = reinterpret_cast<const char*>(Eb) + (size_t)bi * BM * 256;
    const char* wbase = reinterpret_cast<const char*>(Wb);

    // ---- stage A (64 KB) + first B tile (32 KB), pre-swizzled source
    {
        char* sa = reinterpret_cast<char*>(sA);
        #pragma unroll
        for (int j = 0; j < 8; ++j) {
            const int p    = j * 8192 + tid * 16;
            const int row  = p >> 8;
            const int swin = (p & 255) ^ ((row & 7) << 4);
            gload_lds16(ebase + (row << 8) + swin, sa + j * 8192 + wave * 1024);
        }
        char* sb = reinterpret_cast<char*>(sB[0]);
        #pragma unroll
        for (int j = 0; j < 4; ++j) {
            const int p    = j * 8192 + tid * 16;
            const int row  = p >> 8;
            const int swin = (p & 255) ^ ((row & 7) << 4);
            gload_lds16(wbase + ((size_t)(g * BN + row) << 8) + swin,
                        sb + j * 8192 + wave * 1024);
        }
    }
    __syncthreads();

    // ---- A fragments -> registers, once (4 mi x 4 kk x 8 bf16 = 64 VGPR)
    bf16x8 a[4][4];
    {
        const char* sAb = reinterpret_cast<const char*>(sA);
        #pragma unroll
        for (int mi = 0; mi < 4; ++mi) {
            const int row = wm * 64 + mi * 16 + l15;
            #pragma unroll
            for (int kk = 0; kk < 4; ++kk) {
                const int byte = (kk * 64 + g4 * 16) ^ ((row & 7) << 4);
                a[mi][kk] = *reinterpret_cast<const bf16x8*>(sAb + row * 256 + byte);
            }
        }
    }

    float rowsum[4][4] = {};   // [mi][r], persists across all tiles

    int cur = 0;
    for (int t = 0; t < T; ++t) {
        // prefetch next B tile into the other buffer (stays in flight over MFMA)
        if (t + 1 < T) {
            const int ci = g + (t + 1) * NG;
            char* sb = reinterpret_cast<char*>(sB[cur ^ 1]);
            #pragma unroll
            for (int j = 0; j < 4; ++j) {
                const int p    = j * 8192 + tid * 16;
                const int row  = p >> 8;
                const int swin = (p & 255) ^ ((row & 7) << 4);
                gload_lds16(wbase + ((size_t)(ci * BN + row) << 8) + swin,
                            sb + j * 8192 + wave * 1024);
            }
        }

        // current tile: B frags + MFMA
        const char* sBb = reinterpret_cast<const char*>(sB[cur]);
        f32x4 acc[4][4] = {};
        #pragma unroll
        for (int kk = 0; kk < 4; ++kk) {
            bf16x8 b[4];
            #pragma unroll
            for (int ni = 0; ni < 4; ++ni) {
                const int row  = wn * 64 + ni * 16 + l15;
                const int byte = (kk * 64 + g4 * 16) ^ ((row & 7) << 4);
                b[ni] = *reinterpret_cast<const bf16x8*>(sBb + row * 256 + byte);
            }
            #pragma unroll
            for (int mi = 0; mi < 4; ++mi)
                #pragma unroll
                for (int ni = 0; ni < 4; ++ni)
                    acc[mi][ni] = __builtin_amdgcn_mfma_f32_16x16x32_bf16(
                        a[mi][kk], b[ni], acc[mi][ni], 0, 0, 0);
        }

        // epilogue: rowsum += exp2(min(x*92.33 - 92.33, 0))
        // (lower clip free: both sides underflow to 0.0f; upper clip ~9e-6 rel, negligible)
        #pragma unroll
        for (int mi = 0; mi < 4; ++mi) {
            #pragma unroll
            for (int r = 0; r < 4; ++r) {
                float s0 = 0.0f;
                #pragma unroll
                for (int ni = 0; ni < 4; ++ni) {
                    float arg = fminf(fmaf(acc[mi][ni][r], S_LOG2E_F, -S_LOG2E_F), 0.0f);
                    s0 += exp2f(arg);
                }
                rowsum[mi][r] += s0;
            }
        }
        __syncthreads();   // vmcnt+lgkm drain: next-tile buffer ready, cur reusable
        cur ^= 1;
    }

    // ---- one-time reduce across the 16 lanes sharing each output row
    #pragma unroll
    for (int mi = 0; mi < 4; ++mi) {
        #pragma unroll
        for (int r = 0; r < 4; ++r) {
            float s = rowsum[mi][r];
            s += __shfl_xor(s, 1);
            s += __shfl_xor(s, 2);
            s += __shfl_xor(s, 4);
            s += __shfl_xor(s, 8);
            rowsum[mi][r] = s;
        }
    }
    float* rs = reinterpret_cast<float*>(sA);   // sA dead since pre-loop; alias 2x256 f32
    if (l15 == 0) {
        #pragma unroll
        for (int mi = 0; mi < 4; ++mi)
            #pragma unroll
            for (int r = 0; r < 4; ++r)
                rs[wn * 256 + wm * 64 + mi * 16 + g4 * 4 + r] = rowsum[mi][r];
    }
    __syncthreads();
    if (tid < 256)
        P[(size_t)g * B_SZ + bi * 256 + tid] = rs[tid] + rs[256 + tid];
}

// ---- Kernel D1: per-row S reduce (64 partials) + target dot + nll
__global__ void row_fin(const float* __restrict__ P, const __bf16* __restrict__ Eb,
                        const __bf16* __restrict__ Wb, const int* __restrict__ lab,
                        float* __restrict__ nll) {
    __shared__ float red[256];
    const int row = blockIdx.x;
    const int t   = threadIdx.x;

    red[t] = (t < NG) ? P[(size_t)t * B_SZ + row] : 0.0f;
    __syncthreads();
    #pragma unroll
    for (int off = 128; off > 0; off >>= 1) {
        if (t < off) red[t] += red[t + off];
        __syncthreads();
    }
    const float S = red[0];
    __syncthreads();

    const int lb = lab[row];
    float d = 0.0f;
    if (t < 128) d = (float)Eb[row * D_SZ + t] * (float)Wb[(size_t)lb * D_SZ + t];
    red[t] = d;
    __syncthreads();
    #pragma unroll
    for (int off = 128; off > 0; off >>= 1) {
        if (t < off) red[t] += red[t + off];
        __syncthreads();
    }

    if (t == 0) {
        const float ct = red[0];
        const float cc = fminf(fmaxf(ct, -CLIP_F), CLIP_F);
        const float lt = SCALE_F * (cc - MARGIN_F);
        float Sadj = S - exp2f((SCALE_F * cc - SCALE_F) * LOG2E_F)
                       + exp2f((lt - SCALE_F) * LOG2E_F);
        nll[row] = SCALE_F + logf(Sadj) - lt;
    }
}

// ---- Kernel D2: mean over 1024 rows
__global__ void mean_k(const float* __restrict__ nll, float* __restrict__ out) {
    __shared__ float red[1024];
    const int t = threadIdx.x;
    red[t] = nll[t];
    __syncthreads();
    #pragma unroll
    for (int off = 512; off > 0; off >>= 1) {
        if (t < off) red[t] += red[t + off];
        __syncthreads();
    }
    if (t == 0) out[0] = red[0] * (1.0f / 1024.0f);
}

extern "C" void kernel_launch(void* const* d_in, const int* in_sizes, int n_in,
                              void* d_out, int out_size, void* d_ws, size_t ws_size,
                              hipStream_t stream) {
    const float* E   = (const float*)d_in[0];
    const int*   lab = (const int*)d_in[1];
    const float* W   = (const float*)d_in[2];
    float*       out = (float*)d_out;

    char* ws = (char*)d_ws;
    __bf16* Eb  = (__bf16*)ws;                                   // 262,144 B
    __bf16* Wb  = (__bf16*)(ws + 262144);                        // 25,624,576 B (CPAD rows)
    float*  P   = (float*)(ws + 262144 + 25624576);              // 262,144 B
    float*  nll = (float*)(ws + 262144 + 25624576 + 262144);     // 4,096 B

    norm_conv<<<dim3(25280),   256, 0, stream>>>(W, Wb, E, Eb);
    gemm_lse <<<dim3(NG, 4),   512, 0, stream>>>(Eb, Wb, P);
    row_fin  <<<dim3(B_SZ),    256, 0, stream>>>(P, Eb, Wb, lab, nll);
    mean_k   <<<dim3(1),      1024, 0, stream>>>(nll, out);
}